// Round 1
// baseline (375.517 us; speedup 1.0000x reference)
//
#include <hip/hip_runtime.h>
#include <hip/hip_bf16.h>

constexpr int Nn = 100000;   // nodes
constexpr int Ee = 1600000;  // edges
constexpr int Fd = 128;      // in features
constexpr int Dd = 64;       // out features
constexpr float ALPHA = 0.2f;

constexpr int NB = (Nn + 255) / 256;  // 391 scan blocks
constexpr int XPAD = 132;             // x-tile row pitch (floats), 16B-aligned, bank-skewed

// ---------------- GEMM: h = x @ W, ar = h@a_row, ac = h@a_col ----------------
// 256 threads, tile = 64 nodes x 64 cols, 4x4 register tile per thread.
__global__ __launch_bounds__(256, 2) void gemm_scores(
    const float* __restrict__ x, const float* __restrict__ W,
    const float* __restrict__ a_row, const float* __restrict__ a_col,
    float* __restrict__ h, float* __restrict__ ar, float* __restrict__ ac)
{
    __shared__ float Ws[Fd * Dd];      // [k][d], 32 KB
    __shared__ float xs[64 * XPAD];    // [node][k] padded, ~33.8 KB
    __shared__ float as[2 * Dd];       // a_row | a_col

    const int tid = threadIdx.x;
    for (int i = tid; i < Fd * Dd; i += 256) Ws[i] = W[i];
    if (tid < Dd) { as[tid] = a_row[tid]; as[Dd + tid] = a_col[tid]; }

    const int node0 = blockIdx.x * 64;
    {   // stage 64 x-rows as float4 (2048 float4s, 8 per thread)
        const float4* xg = (const float4*)(x + (size_t)node0 * Fd);
        #pragma unroll
        for (int it = 0; it < 8; ++it) {
            int g  = tid + 256 * it;      // float4 idx in tile
            int nd = g >> 5, k4 = g & 31;
            float4 v = make_float4(0.f, 0.f, 0.f, 0.f);
            if (node0 + nd < Nn) v = xg[g];
            *(float4*)&xs[nd * XPAD + k4 * 4] = v;
        }
    }
    __syncthreads();

    const int cg = tid & 15;   // col group: cols cg*4..+3
    const int ng = tid >> 4;   // node group: nodes ng*4..+3
    float acc[4][4] = {};

    for (int k = 0; k < Fd; k += 4) {
        float xr[4][4];
        #pragma unroll
        for (int i = 0; i < 4; ++i) {
            float4 v = *(const float4*)&xs[(ng * 4 + i) * XPAD + k];
            xr[i][0] = v.x; xr[i][1] = v.y; xr[i][2] = v.z; xr[i][3] = v.w;
        }
        #pragma unroll
        for (int kk = 0; kk < 4; ++kk) {
            float4 wv = *(const float4*)&Ws[(k + kk) * Dd + cg * 4];
            float wr[4] = {wv.x, wv.y, wv.z, wv.w};
            #pragma unroll
            for (int i = 0; i < 4; ++i)
                #pragma unroll
                for (int j = 0; j < 4; ++j)
                    acc[i][j] = fmaf(xr[i][kk], wr[j], acc[i][j]);
        }
    }

    #pragma unroll
    for (int i = 0; i < 4; ++i) {
        int node = node0 + ng * 4 + i;
        // per-thread partial scores over this thread's 4 cols
        float pr = acc[i][0] * as[cg * 4 + 0] + acc[i][1] * as[cg * 4 + 1]
                 + acc[i][2] * as[cg * 4 + 2] + acc[i][3] * as[cg * 4 + 3];
        float pc = acc[i][0] * as[Dd + cg * 4 + 0] + acc[i][1] * as[Dd + cg * 4 + 1]
                 + acc[i][2] * as[Dd + cg * 4 + 2] + acc[i][3] * as[Dd + cg * 4 + 3];
        // reduce across the 16 cg lanes (same ng) via xor butterfly
        #pragma unroll
        for (int o = 1; o < 16; o <<= 1) {
            pr += __shfl_xor(pr, o, 64);
            pc += __shfl_xor(pc, o, 64);
        }
        if (node < Nn) {
            float4 hv = make_float4(acc[i][0], acc[i][1], acc[i][2], acc[i][3]);
            *(float4*)&h[(size_t)node * Dd + cg * 4] = hv;
            if (cg == 0) { ar[node] = pr; ac[node] = pc; }
        }
    }
}

// ---------------- CSR build ----------------
__global__ __launch_bounds__(256) void count_edges(const int* __restrict__ rows,
                                                   int* __restrict__ cnt)
{
    int e = blockIdx.x * 256 + threadIdx.x;
    if (e < Ee) atomicAdd(&cnt[rows[e]], 1);
}

__global__ __launch_bounds__(256) void scan_pass1(const int* __restrict__ cnt,
                                                  int* __restrict__ bsum)
{
    __shared__ int wsum[4];
    int i = blockIdx.x * 256 + threadIdx.x;
    int v = (i < Nn) ? cnt[i] : 0;
    #pragma unroll
    for (int o = 32; o > 0; o >>= 1) v += __shfl_down(v, o, 64);
    int lane = threadIdx.x & 63, w = threadIdx.x >> 6;
    if (lane == 0) wsum[w] = v;
    __syncthreads();
    if (threadIdx.x == 0) bsum[blockIdx.x] = wsum[0] + wsum[1] + wsum[2] + wsum[3];
}

// single block, 512 threads; in-place exclusive scan of bsum[0..NB), total -> off[Nn]
__global__ __launch_bounds__(512) void scan_pass2(int* __restrict__ bscr,
                                                  int* __restrict__ off_total)
{
    __shared__ int ws[8];
    int tid = threadIdx.x;
    int v = (tid < NB) ? bscr[tid] : 0;
    int lane = tid & 63, w = tid >> 6;
    int incl = v;
    #pragma unroll
    for (int o = 1; o < 64; o <<= 1) {
        int y = __shfl_up(incl, o, 64);
        if (lane >= o) incl += y;
    }
    if (lane == 63) ws[w] = incl;
    __syncthreads();
    int pre = 0;
    for (int j = 0; j < w; ++j) pre += ws[j];
    if (tid < NB) bscr[tid] = pre + incl - v;
    if (tid == 511) off_total[0] = pre + incl;  // grand total == Ee
}

__global__ __launch_bounds__(256) void scan_pass3(const int* __restrict__ cnt,
                                                  const int* __restrict__ boff,
                                                  int* __restrict__ off,
                                                  int* __restrict__ wp)
{
    __shared__ int ws[4];
    int i = blockIdx.x * 256 + threadIdx.x;
    int v = (i < Nn) ? cnt[i] : 0;
    int lane = threadIdx.x & 63, w = threadIdx.x >> 6;
    int incl = v;
    #pragma unroll
    for (int o = 1; o < 64; o <<= 1) {
        int y = __shfl_up(incl, o, 64);
        if (lane >= o) incl += y;
    }
    if (lane == 63) ws[w] = incl;
    __syncthreads();
    int pre = 0;
    for (int j = 0; j < w; ++j) pre += ws[j];
    int excl = boff[blockIdx.x] + pre + incl - v;
    if (i < Nn) { off[i] = excl; wp[i] = excl; }
}

// ---------------- edge scores + bucket scatter (sorted-by-row) ----------------
__global__ __launch_bounds__(256) void edge_scatter(
    const int* __restrict__ rows, const int* __restrict__ cols,
    const float* __restrict__ ar, const float* __restrict__ ac,
    int* __restrict__ wp, int* __restrict__ col_s, float* __restrict__ ex_s)
{
    int e = blockIdx.x * 256 + threadIdx.x;
    if (e >= Ee) return;
    int r = rows[e], c = cols[e];
    float sc = ar[r] + ac[c];
    sc = sc > 0.f ? sc : ALPHA * sc;
    float ex = __expf(sc);  // max-subtraction removed: mathematically identical softmax
    int slot = atomicAdd(&wp[r], 1);
    col_s[slot] = c;
    ex_s[slot] = ex;
}

// ---------------- SpMM: out[i] = (1/sum_w) * sum_j w_ij * h[j,:] ----------------
// 16 lanes x float4 per node; 16 nodes per 256-thread block. No atomics.
__global__ __launch_bounds__(256) void spmm(
    const float* __restrict__ h, const int* __restrict__ off,
    const int* __restrict__ col_s, const float* __restrict__ ex_s,
    float* __restrict__ out)
{
    int tid  = threadIdx.x;
    int node = blockIdx.x * 16 + (tid >> 4);
    int lq   = tid & 15;  // covers cols lq*4..+3
    if (node >= Nn) return;
    int s0 = off[node], s1 = off[node + 1];
    const float4* h4 = (const float4*)h;
    float4 acc = make_float4(0.f, 0.f, 0.f, 0.f);
    float wsum = 0.f;
    for (int s = s0; s < s1; ++s) {
        int c = col_s[s];
        float wgt = ex_s[s];
        wsum += wgt;
        float4 hv = h4[(size_t)c * 16 + lq];
        acc.x = fmaf(wgt, hv.x, acc.x);
        acc.y = fmaf(wgt, hv.y, acc.y);
        acc.z = fmaf(wgt, hv.z, acc.z);
        acc.w = fmaf(wgt, hv.w, acc.w);
    }
    float inv = (s1 > s0) ? 1.f / wsum : 0.f;
    float4 o = make_float4(acc.x * inv, acc.y * inv, acc.z * inv, acc.w * inv);
    ((float4*)out)[(size_t)node * 16 + lq] = o;
}

// ---------------- launch ----------------
extern "C" void kernel_launch(void* const* d_in, const int* in_sizes, int n_in,
                              void* d_out, int out_size, void* d_ws, size_t ws_size,
                              hipStream_t stream)
{
    const float* x     = (const float*)d_in[0];
    const int*   rows  = (const int*)d_in[1];
    const int*   cols  = (const int*)d_in[2];
    const float* W     = (const float*)d_in[3];
    const float* a_row = (const float*)d_in[4];
    const float* a_col = (const float*)d_in[5];
    float* out = (float*)d_out;

    char* ws = (char*)d_ws;
    size_t o = 0;
    float* h    = (float*)(ws + o); o += (size_t)Nn * Dd * 4;  // 25.6 MB
    float* ar   = (float*)(ws + o); o += (size_t)Nn * 4;
    float* ac   = (float*)(ws + o); o += (size_t)Nn * 4;
    int*   cnt  = (int*)(ws + o);   o += (size_t)Nn * 4;
    int*   off  = (int*)(ws + o);   o += (size_t)(Nn + 4) * 4; // off[Nn] = Ee
    int*   wp   = (int*)(ws + o);   o += (size_t)Nn * 4;
    int*   bscr = (int*)(ws + o);   o += 512 * 4;
    int*   col_s = (int*)(ws + o);  o += (size_t)Ee * 4;       // 6.4 MB
    float* ex_s  = (float*)(ws + o); o += (size_t)Ee * 4;      // 6.4 MB
    // total ~40 MB of ws

    hipMemsetAsync(cnt, 0, (size_t)Nn * 4, stream);

    count_edges<<<(Ee + 255) / 256, 256, 0, stream>>>(rows, cnt);
    scan_pass1<<<NB, 256, 0, stream>>>(cnt, bscr);
    scan_pass2<<<1, 512, 0, stream>>>(bscr, off + Nn);
    scan_pass3<<<NB, 256, 0, stream>>>(cnt, bscr, off, wp);

    gemm_scores<<<(Nn + 63) / 64, 256, 0, stream>>>(x, W, a_row, a_col, h, ar, ac);
    edge_scatter<<<(Ee + 255) / 256, 256, 0, stream>>>(rows, cols, ar, ac, wp, col_s, ex_s);
    spmm<<<(Nn + 15) / 16, 256, 0, stream>>>(h, off, col_s, ex_s, out);
}

// Round 2
// 357.269 us; speedup vs baseline: 1.0511x; 1.0511x over previous
//
#include <hip/hip_runtime.h>
#include <hip/hip_bf16.h>

constexpr int Nn = 100000;   // nodes
constexpr int Ee = 1600000;  // edges
constexpr int Fd = 128;      // in features
constexpr int Dd = 64;       // out features
constexpr float ALPHA = 0.2f;

constexpr int NB = (Nn + 255) / 256;  // 391 scan blocks
constexpr int XPAD = 132;             // x-tile row pitch (floats), 16B-aligned, bank-skewed

// ---------------- GEMM: h = x @ W, ar = h@a_row, ac = h@a_col ----------------
// 256 threads, tile = 64 nodes x 64 cols, 4x4 register tile per thread.
__global__ __launch_bounds__(256, 2) void gemm_scores(
    const float* __restrict__ x, const float* __restrict__ W,
    const float* __restrict__ a_row, const float* __restrict__ a_col,
    float* __restrict__ h, float* __restrict__ ar, float* __restrict__ ac)
{
    __shared__ float Ws[Fd * Dd];      // [k][d], 32 KB
    __shared__ float xs[64 * XPAD];    // [node][k] padded, ~33.8 KB
    __shared__ float as[2 * Dd];       // a_row | a_col

    const int tid = threadIdx.x;
    for (int i = tid; i < Fd * Dd; i += 256) Ws[i] = W[i];
    if (tid < Dd) { as[tid] = a_row[tid]; as[Dd + tid] = a_col[tid]; }

    const int node0 = blockIdx.x * 64;
    {   // stage 64 x-rows as float4 (2048 float4s, 8 per thread)
        const float4* xg = (const float4*)(x + (size_t)node0 * Fd);
        #pragma unroll
        for (int it = 0; it < 8; ++it) {
            int g  = tid + 256 * it;      // float4 idx in tile
            int nd = g >> 5, k4 = g & 31;
            float4 v = make_float4(0.f, 0.f, 0.f, 0.f);
            if (node0 + nd < Nn) v = xg[g];
            *(float4*)&xs[nd * XPAD + k4 * 4] = v;
        }
    }
    __syncthreads();

    const int cg = tid & 15;   // col group: cols cg*4..+3
    const int ng = tid >> 4;   // node group: nodes ng*4..+3
    float acc[4][4] = {};

    for (int k = 0; k < Fd; k += 4) {
        float xr[4][4];
        #pragma unroll
        for (int i = 0; i < 4; ++i) {
            float4 v = *(const float4*)&xs[(ng * 4 + i) * XPAD + k];
            xr[i][0] = v.x; xr[i][1] = v.y; xr[i][2] = v.z; xr[i][3] = v.w;
        }
        #pragma unroll
        for (int kk = 0; kk < 4; ++kk) {
            float4 wv = *(const float4*)&Ws[(k + kk) * Dd + cg * 4];
            float wr[4] = {wv.x, wv.y, wv.z, wv.w};
            #pragma unroll
            for (int i = 0; i < 4; ++i)
                #pragma unroll
                for (int j = 0; j < 4; ++j)
                    acc[i][j] = fmaf(xr[i][kk], wr[j], acc[i][j]);
        }
    }

    #pragma unroll
    for (int i = 0; i < 4; ++i) {
        int node = node0 + ng * 4 + i;
        float pr = acc[i][0] * as[cg * 4 + 0] + acc[i][1] * as[cg * 4 + 1]
                 + acc[i][2] * as[cg * 4 + 2] + acc[i][3] * as[cg * 4 + 3];
        float pc = acc[i][0] * as[Dd + cg * 4 + 0] + acc[i][1] * as[Dd + cg * 4 + 1]
                 + acc[i][2] * as[Dd + cg * 4 + 2] + acc[i][3] * as[Dd + cg * 4 + 3];
        #pragma unroll
        for (int o = 1; o < 16; o <<= 1) {
            pr += __shfl_xor(pr, o, 64);
            pc += __shfl_xor(pc, o, 64);
        }
        if (node < Nn) {
            float4 hv = make_float4(acc[i][0], acc[i][1], acc[i][2], acc[i][3]);
            *(float4*)&h[(size_t)node * Dd + cg * 4] = hv;
            if (cg == 0) { ar[node] = pr; ac[node] = pc; }
        }
    }
}

// ---------------- CSR build ----------------
__global__ __launch_bounds__(256) void count_edges(const int* __restrict__ rows,
                                                   int* __restrict__ cnt)
{
    int e = blockIdx.x * 256 + threadIdx.x;
    if (e < Ee) atomicAdd(&cnt[rows[e]], 1);
}

__global__ __launch_bounds__(256) void scan_pass1(const int* __restrict__ cnt,
                                                  int* __restrict__ bsum)
{
    __shared__ int wsum[4];
    int i = blockIdx.x * 256 + threadIdx.x;
    int v = (i < Nn) ? cnt[i] : 0;
    #pragma unroll
    for (int o = 32; o > 0; o >>= 1) v += __shfl_down(v, o, 64);
    int lane = threadIdx.x & 63, w = threadIdx.x >> 6;
    if (lane == 0) wsum[w] = v;
    __syncthreads();
    if (threadIdx.x == 0) bsum[blockIdx.x] = wsum[0] + wsum[1] + wsum[2] + wsum[3];
}

// single block, 512 threads; in-place exclusive scan of bsum[0..NB), total -> off[Nn]
__global__ __launch_bounds__(512) void scan_pass2(int* __restrict__ bscr,
                                                  int* __restrict__ off_total)
{
    __shared__ int ws[8];
    int tid = threadIdx.x;
    int v = (tid < NB) ? bscr[tid] : 0;
    int lane = tid & 63, w = tid >> 6;
    int incl = v;
    #pragma unroll
    for (int o = 1; o < 64; o <<= 1) {
        int y = __shfl_up(incl, o, 64);
        if (lane >= o) incl += y;
    }
    if (lane == 63) ws[w] = incl;
    __syncthreads();
    int pre = 0;
    for (int j = 0; j < w; ++j) pre += ws[j];
    if (tid < NB) bscr[tid] = pre + incl - v;
    if (tid == 511) off_total[0] = pre + incl;  // grand total == Ee
}

__global__ __launch_bounds__(256) void scan_pass3(const int* __restrict__ cnt,
                                                  const int* __restrict__ boff,
                                                  int* __restrict__ off,
                                                  int* __restrict__ wp)
{
    __shared__ int ws[4];
    int i = blockIdx.x * 256 + threadIdx.x;
    int v = (i < Nn) ? cnt[i] : 0;
    int lane = threadIdx.x & 63, w = threadIdx.x >> 6;
    int incl = v;
    #pragma unroll
    for (int o = 1; o < 64; o <<= 1) {
        int y = __shfl_up(incl, o, 64);
        if (lane >= o) incl += y;
    }
    if (lane == 63) ws[w] = incl;
    __syncthreads();
    int pre = 0;
    for (int j = 0; j < w; ++j) pre += ws[j];
    int excl = boff[blockIdx.x] + pre + incl - v;
    if (i < Nn) { off[i] = excl; wp[i] = excl; }
}

// ---------------- edge scores + bucket scatter (sorted-by-row) ----------------
// Packed (col, ex) as one float2 -> ONE dirty cacheline per edge instead of two.
__global__ __launch_bounds__(256) void edge_scatter(
    const int* __restrict__ rows, const int* __restrict__ cols,
    const float* __restrict__ ar, const float* __restrict__ ac,
    int* __restrict__ wp, float2* __restrict__ ce_s)
{
    int e = blockIdx.x * 256 + threadIdx.x;
    if (e >= Ee) return;
    int r = rows[e], c = cols[e];
    float sc = ar[r] + ac[c];
    sc = sc > 0.f ? sc : ALPHA * sc;
    float ex = __expf(sc);  // max-subtraction removed: mathematically identical softmax
    int slot = atomicAdd(&wp[r], 1);
    ce_s[slot] = make_float2(__int_as_float(c), ex);
}

// ---------------- SpMM: out[i] = (1/sum_w) * sum_j w_ij * h[j,:] ----------------
// 16 lanes x float4 per node; 16 nodes per 256-thread block. No atomics.
__global__ __launch_bounds__(256) void spmm(
    const float* __restrict__ h, const int* __restrict__ off,
    const float2* __restrict__ ce_s, float* __restrict__ out)
{
    int tid  = threadIdx.x;
    int node = blockIdx.x * 16 + (tid >> 4);
    int lq   = tid & 15;  // covers cols lq*4..+3
    if (node >= Nn) return;
    int s0 = off[node], s1 = off[node + 1];
    const float4* h4 = (const float4*)h;
    float4 acc = make_float4(0.f, 0.f, 0.f, 0.f);
    float wsum = 0.f;
    for (int s = s0; s < s1; ++s) {
        float2 p = ce_s[s];           // broadcast across the 16-lane group
        int c = __float_as_int(p.x);
        float wgt = p.y;
        wsum += wgt;
        float4 hv = h4[(size_t)c * 16 + lq];
        acc.x = fmaf(wgt, hv.x, acc.x);
        acc.y = fmaf(wgt, hv.y, acc.y);
        acc.z = fmaf(wgt, hv.z, acc.z);
        acc.w = fmaf(wgt, hv.w, acc.w);
    }
    float inv = (s1 > s0) ? 1.f / wsum : 0.f;
    float4 o = make_float4(acc.x * inv, acc.y * inv, acc.z * inv, acc.w * inv);
    ((float4*)out)[(size_t)node * 16 + lq] = o;
}

// ---------------- launch ----------------
extern "C" void kernel_launch(void* const* d_in, const int* in_sizes, int n_in,
                              void* d_out, int out_size, void* d_ws, size_t ws_size,
                              hipStream_t stream)
{
    const float* x     = (const float*)d_in[0];
    const int*   rows  = (const int*)d_in[1];
    const int*   cols  = (const int*)d_in[2];
    const float* W     = (const float*)d_in[3];
    const float* a_row = (const float*)d_in[4];
    const float* a_col = (const float*)d_in[5];
    float* out = (float*)d_out;

    char* ws = (char*)d_ws;
    size_t o = 0;
    float* h    = (float*)(ws + o); o += (size_t)Nn * Dd * 4;  // 25.6 MB
    float* ar   = (float*)(ws + o); o += (size_t)Nn * 4;
    float* ac   = (float*)(ws + o); o += (size_t)Nn * 4;
    int*   cnt  = (int*)(ws + o);   o += (size_t)Nn * 4;
    int*   off  = (int*)(ws + o);   o += (size_t)(Nn + 4) * 4; // off[Nn] = Ee
    int*   wp   = (int*)(ws + o);   o += (size_t)Nn * 4;
    int*   bscr = (int*)(ws + o);   o += 512 * 4;
    float2* ce_s = (float2*)(ws + o); o += (size_t)Ee * 8;     // 12.8 MB packed (col, ex)

    hipMemsetAsync(cnt, 0, (size_t)Nn * 4, stream);

    count_edges<<<(Ee + 255) / 256, 256, 0, stream>>>(rows, cnt);
    scan_pass1<<<NB, 256, 0, stream>>>(cnt, bscr);
    scan_pass2<<<1, 512, 0, stream>>>(bscr, off + Nn);
    scan_pass3<<<NB, 256, 0, stream>>>(cnt, bscr, off, wp);

    gemm_scores<<<(Nn + 63) / 64, 256, 0, stream>>>(x, W, a_row, a_col, h, ar, ac);
    edge_scatter<<<(Ee + 255) / 256, 256, 0, stream>>>(rows, cols, ar, ac, wp, ce_s);
    spmm<<<(Nn + 15) / 16, 256, 0, stream>>>(h, off, ce_s, out);
}

// Round 3
// 344.855 us; speedup vs baseline: 1.0889x; 1.0360x over previous
//
#include <hip/hip_runtime.h>
#include <hip/hip_bf16.h>

constexpr int Nn = 100000;   // nodes
constexpr int Ee = 1600000;  // edges
constexpr int Fd = 128;      // in features
constexpr int Dd = 64;       // out features
constexpr float ALPHA = 0.2f;

constexpr int NB = (Nn + 255) / 256;  // 391 scan blocks
constexpr int XPAD = 132;             // x-tile row pitch (floats), 16B-aligned, bank-skewed

constexpr int BSH   = 9;                        // bucket = row >> 9 (512 rows/bucket)
constexpr int NBUCK = (Nn + (1 << BSH) - 1) >> BSH;  // 196
constexpr int BCAP  = 48;                       // LDS entries per bucket
constexpr int BINB  = 512;                      // edge_bin blocks

// ---------------- GEMM: h = x @ W, ar = h@a_row, ac = h@a_col ----------------
__global__ __launch_bounds__(256, 2) void gemm_scores(
    const float* __restrict__ x, const float* __restrict__ W,
    const float* __restrict__ a_row, const float* __restrict__ a_col,
    float* __restrict__ h, float* __restrict__ ar, float* __restrict__ ac)
{
    __shared__ float Ws[Fd * Dd];      // [k][d], 32 KB
    __shared__ float xs[64 * XPAD];    // [node][k] padded
    __shared__ float as[2 * Dd];       // a_row | a_col

    const int tid = threadIdx.x;
    for (int i = tid; i < Fd * Dd; i += 256) Ws[i] = W[i];
    if (tid < Dd) { as[tid] = a_row[tid]; as[Dd + tid] = a_col[tid]; }

    const int node0 = blockIdx.x * 64;
    {
        const float4* xg = (const float4*)(x + (size_t)node0 * Fd);
        #pragma unroll
        for (int it = 0; it < 8; ++it) {
            int g  = tid + 256 * it;
            int nd = g >> 5, k4 = g & 31;
            float4 v = make_float4(0.f, 0.f, 0.f, 0.f);
            if (node0 + nd < Nn) v = xg[g];
            *(float4*)&xs[nd * XPAD + k4 * 4] = v;
        }
    }
    __syncthreads();

    const int cg = tid & 15;
    const int ng = tid >> 4;
    float acc[4][4] = {};

    for (int k = 0; k < Fd; k += 4) {
        float xr[4][4];
        #pragma unroll
        for (int i = 0; i < 4; ++i) {
            float4 v = *(const float4*)&xs[(ng * 4 + i) * XPAD + k];
            xr[i][0] = v.x; xr[i][1] = v.y; xr[i][2] = v.z; xr[i][3] = v.w;
        }
        #pragma unroll
        for (int kk = 0; kk < 4; ++kk) {
            float4 wv = *(const float4*)&Ws[(k + kk) * Dd + cg * 4];
            float wr[4] = {wv.x, wv.y, wv.z, wv.w};
            #pragma unroll
            for (int i = 0; i < 4; ++i)
                #pragma unroll
                for (int j = 0; j < 4; ++j)
                    acc[i][j] = fmaf(xr[i][kk], wr[j], acc[i][j]);
        }
    }

    #pragma unroll
    for (int i = 0; i < 4; ++i) {
        int node = node0 + ng * 4 + i;
        float pr = acc[i][0] * as[cg * 4 + 0] + acc[i][1] * as[cg * 4 + 1]
                 + acc[i][2] * as[cg * 4 + 2] + acc[i][3] * as[cg * 4 + 3];
        float pc = acc[i][0] * as[Dd + cg * 4 + 0] + acc[i][1] * as[Dd + cg * 4 + 1]
                 + acc[i][2] * as[Dd + cg * 4 + 2] + acc[i][3] * as[Dd + cg * 4 + 3];
        #pragma unroll
        for (int o = 1; o < 16; o <<= 1) {
            pr += __shfl_xor(pr, o, 64);
            pc += __shfl_xor(pc, o, 64);
        }
        if (node < Nn) {
            float4 hv = make_float4(acc[i][0], acc[i][1], acc[i][2], acc[i][3]);
            *(float4*)&h[(size_t)node * Dd + cg * 4] = hv;
            if (cg == 0) { ar[node] = pr; ac[node] = pc; }
        }
    }
}

// ---------------- CSR build ----------------
__global__ __launch_bounds__(256) void count_edges(const int* __restrict__ rows,
                                                   int* __restrict__ cnt)
{
    int e = blockIdx.x * 256 + threadIdx.x;
    if (e < Ee) atomicAdd(&cnt[rows[e]], 1);
}

__global__ __launch_bounds__(256) void scan_pass1(const int* __restrict__ cnt,
                                                  int* __restrict__ bsum)
{
    __shared__ int wsum[4];
    int i = blockIdx.x * 256 + threadIdx.x;
    int v = (i < Nn) ? cnt[i] : 0;
    #pragma unroll
    for (int o = 32; o > 0; o >>= 1) v += __shfl_down(v, o, 64);
    int lane = threadIdx.x & 63, w = threadIdx.x >> 6;
    if (lane == 0) wsum[w] = v;
    __syncthreads();
    if (threadIdx.x == 0) bsum[blockIdx.x] = wsum[0] + wsum[1] + wsum[2] + wsum[3];
}

__global__ __launch_bounds__(512) void scan_pass2(int* __restrict__ bscr,
                                                  int* __restrict__ off_total)
{
    __shared__ int ws[8];
    int tid = threadIdx.x;
    int v = (tid < NB) ? bscr[tid] : 0;
    int lane = tid & 63, w = tid >> 6;
    int incl = v;
    #pragma unroll
    for (int o = 1; o < 64; o <<= 1) {
        int y = __shfl_up(incl, o, 64);
        if (lane >= o) incl += y;
    }
    if (lane == 63) ws[w] = incl;
    __syncthreads();
    int pre = 0;
    for (int j = 0; j < w; ++j) pre += ws[j];
    if (tid < NB) bscr[tid] = pre + incl - v;
    if (tid == 511) off_total[0] = pre + incl;  // == Ee
}

__global__ __launch_bounds__(256) void scan_pass3(const int* __restrict__ cnt,
                                                  const int* __restrict__ boff_blk,
                                                  int* __restrict__ off,
                                                  int* __restrict__ wp)
{
    __shared__ int ws[4];
    int i = blockIdx.x * 256 + threadIdx.x;
    int v = (i < Nn) ? cnt[i] : 0;
    int lane = threadIdx.x & 63, w = threadIdx.x >> 6;
    int incl = v;
    #pragma unroll
    for (int o = 1; o < 64; o <<= 1) {
        int y = __shfl_up(incl, o, 64);
        if (lane >= o) incl += y;
    }
    if (lane == 63) ws[w] = incl;
    __syncthreads();
    int pre = 0;
    for (int j = 0; j < w; ++j) pre += ws[j];
    int excl = boff_blk[blockIdx.x] + pre + incl - v;
    if (i < Nn) { off[i] = excl; wp[i] = excl; }
}

// bucket write pointers + bucket boundary offsets from off[]
__global__ void bwp_boff_init(const int* __restrict__ off,
                              int* __restrict__ bwp, int* __restrict__ boff)
{
    int b = threadIdx.x;
    if (b <= NBUCK) {
        int idx = b << BSH; if (idx > Nn) idx = Nn;
        int v = off[idx];
        boff[b] = v;
        if (b < NBUCK) bwp[b] = v;
    }
}

// ---------------- Pass A: LDS-binned edge staging ----------------
// Bins edges by row-bucket in LDS, bulk-appends contiguous chunks per bucket.
__global__ __launch_bounds__(256, 2) void edge_bin(
    const int* __restrict__ rows, const int* __restrict__ cols,
    int* __restrict__ bwp, int2* __restrict__ binned)
{
    __shared__ int2 buf[NBUCK * BCAP];   // ~75 KB
    __shared__ int  lcnt[NBUCK];
    __shared__ int  lbase[NBUCK];

    const int tid = threadIdx.x;
    for (int b = tid; b < NBUCK; b += 256) lcnt[b] = 0;
    __syncthreads();

    const int per = (Ee + BINB - 1) / BINB;   // 3125
    const int e0 = blockIdx.x * per;
    const int e1 = min(e0 + per, Ee);

    int tile = 0;
    for (int base = e0; base < e1; base += 256) {
        int e = base + tid;
        if (e < e1) {
            int r = rows[e], c = cols[e];
            int b = r >> BSH;
            int pos = atomicAdd(&lcnt[b], 1);
            if (pos < BCAP) buf[b * BCAP + pos] = make_int2(r, c);
            else {  // rare overflow: direct append
                int slot = atomicAdd(&bwp[b], 1);
                binned[slot] = make_int2(r, c);
            }
        }
        if (++tile == 16) {  // flush (not reached at BINB=512; kept for safety)
            tile = 0;
            __syncthreads();
            for (int b = tid; b < NBUCK; b += 256)
                lbase[b] = atomicAdd(&bwp[b], min(lcnt[b], BCAP));
            __syncthreads();
            int w = tid >> 6, lane = tid & 63;
            for (int b = w; b < NBUCK; b += 4) {
                int cnt = min(lcnt[b], BCAP);
                int gb = lbase[b];
                for (int i = lane; i < cnt; i += 64)
                    binned[gb + i] = buf[b * BCAP + i];
            }
            __syncthreads();
            for (int b = tid; b < NBUCK; b += 256) lcnt[b] = 0;
            __syncthreads();
        }
    }
    // final flush
    __syncthreads();
    for (int b = tid; b < NBUCK; b += 256)
        lbase[b] = atomicAdd(&bwp[b], min(lcnt[b], BCAP));
    __syncthreads();
    int w = tid >> 6, lane = tid & 63;
    for (int b = w; b < NBUCK; b += 4) {
        int cnt = min(lcnt[b], BCAP);
        int gb = lbase[b];
        for (int i = lane; i < cnt; i += 64)
            binned[gb + i] = buf[b * BCAP + i];
    }
}

// ---------------- Pass B: bucket-local scatter to final CSR ----------------
// One block per bucket: wp window ~2KB, ce_s window ~64KB -> stays in one XCD's L2.
__global__ __launch_bounds__(256) void bucket_to_csr(
    const int2* __restrict__ binned, const int* __restrict__ boff,
    const float* __restrict__ ar, const float* __restrict__ ac,
    int* __restrict__ wp, float2* __restrict__ ce_s)
{
    int b = blockIdx.x;
    int s0 = boff[b], s1 = boff[b + 1];
    for (int s = s0 + threadIdx.x; s < s1; s += 256) {
        int2 rc = binned[s];
        float sc = ar[rc.x] + ac[rc.y];
        sc = sc > 0.f ? sc : ALPHA * sc;
        float ex = __expf(sc);
        int slot = atomicAdd(&wp[rc.x], 1);
        ce_s[slot] = make_float2(__int_as_float(rc.y), ex);
    }
}

// ---------------- SpMM ----------------
__global__ __launch_bounds__(256) void spmm(
    const float* __restrict__ h, const int* __restrict__ off,
    const float2* __restrict__ ce_s, float* __restrict__ out)
{
    int tid  = threadIdx.x;
    int node = blockIdx.x * 16 + (tid >> 4);
    int lq   = tid & 15;
    if (node >= Nn) return;
    int s0 = off[node], s1 = off[node + 1];
    const float4* h4 = (const float4*)h;
    float4 acc = make_float4(0.f, 0.f, 0.f, 0.f);
    float wsum = 0.f;
    for (int s = s0; s < s1; ++s) {
        float2 p = ce_s[s];
        int c = __float_as_int(p.x);
        float wgt = p.y;
        wsum += wgt;
        float4 hv = h4[(size_t)c * 16 + lq];
        acc.x = fmaf(wgt, hv.x, acc.x);
        acc.y = fmaf(wgt, hv.y, acc.y);
        acc.z = fmaf(wgt, hv.z, acc.z);
        acc.w = fmaf(wgt, hv.w, acc.w);
    }
    float inv = (s1 > s0) ? 1.f / wsum : 0.f;
    float4 o = make_float4(acc.x * inv, acc.y * inv, acc.z * inv, acc.w * inv);
    ((float4*)out)[(size_t)node * 16 + lq] = o;
}

// ---------------- launch ----------------
extern "C" void kernel_launch(void* const* d_in, const int* in_sizes, int n_in,
                              void* d_out, int out_size, void* d_ws, size_t ws_size,
                              hipStream_t stream)
{
    const float* x     = (const float*)d_in[0];
    const int*   rows  = (const int*)d_in[1];
    const int*   cols  = (const int*)d_in[2];
    const float* W     = (const float*)d_in[3];
    const float* a_row = (const float*)d_in[4];
    const float* a_col = (const float*)d_in[5];
    float* out = (float*)d_out;

    char* ws = (char*)d_ws;
    size_t o = 0;
    float* h    = (float*)(ws + o); o += (size_t)Nn * Dd * 4;   // 25.6 MB
    float* ar   = (float*)(ws + o); o += (size_t)Nn * 4;
    float* ac   = (float*)(ws + o); o += (size_t)Nn * 4;
    int*   cnt  = (int*)(ws + o);   o += (size_t)Nn * 4;
    int*   off  = (int*)(ws + o);   o += (size_t)(Nn + 4) * 4;  // off[Nn] = Ee
    int*   wp   = (int*)(ws + o);   o += (size_t)Nn * 4;
    int*   bscr = (int*)(ws + o);   o += 512 * 4;
    int*   bwp  = (int*)(ws + o);   o += 256 * 4;
    int*   boff = (int*)(ws + o);   o += 256 * 4;
    float2* ce_s  = (float2*)(ws + o); o += (size_t)Ee * 8;     // 12.8 MB
    int2*   binned = (int2*)(ws + o);  o += (size_t)Ee * 8;     // 12.8 MB

    hipMemsetAsync(cnt, 0, (size_t)Nn * 4, stream);

    gemm_scores<<<(Nn + 63) / 64, 256, 0, stream>>>(x, W, a_row, a_col, h, ar, ac);
    count_edges<<<(Ee + 255) / 256, 256, 0, stream>>>(rows, cnt);
    scan_pass1<<<NB, 256, 0, stream>>>(cnt, bscr);
    scan_pass2<<<1, 512, 0, stream>>>(bscr, off + Nn);
    scan_pass3<<<NB, 256, 0, stream>>>(cnt, bscr, off, wp);
    bwp_boff_init<<<1, 256, 0, stream>>>(off, bwp, boff);
    edge_bin<<<BINB, 256, 0, stream>>>(rows, cols, bwp, binned);
    bucket_to_csr<<<NBUCK, 256, 0, stream>>>(binned, boff, ar, ac, wp, ce_s);
    spmm<<<(Nn + 15) / 16, 256, 0, stream>>>(h, off, ce_s, out);
}

// Round 4
// 253.235 us; speedup vs baseline: 1.4829x; 1.3618x over previous
//
#include <hip/hip_runtime.h>
#include <hip/hip_bf16.h>

constexpr int Nn = 100000;   // nodes
constexpr int Ee = 1600000;  // edges
constexpr int Fd = 128;      // in features
constexpr int Dd = 64;       // out features
constexpr float ALPHA = 0.2f;

constexpr int XPAD = 132;    // x-tile row pitch (floats)

constexpr int BSH    = 8;                              // 256 rows per bucket
constexpr int NBUCK  = (Nn + (1 << BSH) - 1) >> BSH;   // 391
constexpr int BSLACK = 8192;                           // slack region per bucket (mean 4096)
constexpr int BCAP   = 24;                             // LDS entries per bucket (mean 8)
constexpr int BINB   = 512;                            // edge_bin blocks

__device__ __forceinline__ unsigned short f2bf(float f) {  // RTNE
    unsigned int u = __float_as_uint(f);
    u += 0x7fffu + ((u >> 16) & 1u);
    return (unsigned short)(u >> 16);
}
__device__ __forceinline__ float bf2f(unsigned short s) {
    return __uint_as_float((unsigned int)s << 16);
}

// ---------------- GEMM: h(bf16) = x @ W, ar = h@a_row, ac = h@a_col ----------------
__global__ __launch_bounds__(256, 2) void gemm_scores(
    const float* __restrict__ x, const float* __restrict__ W,
    const float* __restrict__ a_row, const float* __restrict__ a_col,
    unsigned short* __restrict__ h, float* __restrict__ ar, float* __restrict__ ac)
{
    __shared__ float Ws[Fd * Dd];
    __shared__ float xs[64 * XPAD];
    __shared__ float as[2 * Dd];

    const int tid = threadIdx.x;
    for (int i = tid; i < Fd * Dd; i += 256) Ws[i] = W[i];
    if (tid < Dd) { as[tid] = a_row[tid]; as[Dd + tid] = a_col[tid]; }

    const int node0 = blockIdx.x * 64;
    {
        const float4* xg = (const float4*)(x + (size_t)node0 * Fd);
        #pragma unroll
        for (int it = 0; it < 8; ++it) {
            int g  = tid + 256 * it;
            int nd = g >> 5, k4 = g & 31;
            float4 v = make_float4(0.f, 0.f, 0.f, 0.f);
            if (node0 + nd < Nn) v = xg[g];
            *(float4*)&xs[nd * XPAD + k4 * 4] = v;
        }
    }
    __syncthreads();

    const int cg = tid & 15;
    const int ng = tid >> 4;
    float acc[4][4] = {};

    for (int k = 0; k < Fd; k += 4) {
        float xr[4][4];
        #pragma unroll
        for (int i = 0; i < 4; ++i) {
            float4 v = *(const float4*)&xs[(ng * 4 + i) * XPAD + k];
            xr[i][0] = v.x; xr[i][1] = v.y; xr[i][2] = v.z; xr[i][3] = v.w;
        }
        #pragma unroll
        for (int kk = 0; kk < 4; ++kk) {
            float4 wv = *(const float4*)&Ws[(k + kk) * Dd + cg * 4];
            float wr[4] = {wv.x, wv.y, wv.z, wv.w};
            #pragma unroll
            for (int i = 0; i < 4; ++i)
                #pragma unroll
                for (int j = 0; j < 4; ++j)
                    acc[i][j] = fmaf(xr[i][kk], wr[j], acc[i][j]);
        }
    }

    #pragma unroll
    for (int i = 0; i < 4; ++i) {
        int node = node0 + ng * 4 + i;
        float pr = acc[i][0] * as[cg * 4 + 0] + acc[i][1] * as[cg * 4 + 1]
                 + acc[i][2] * as[cg * 4 + 2] + acc[i][3] * as[cg * 4 + 3];
        float pc = acc[i][0] * as[Dd + cg * 4 + 0] + acc[i][1] * as[Dd + cg * 4 + 1]
                 + acc[i][2] * as[Dd + cg * 4 + 2] + acc[i][3] * as[Dd + cg * 4 + 3];
        #pragma unroll
        for (int o = 1; o < 16; o <<= 1) {
            pr += __shfl_xor(pr, o, 64);
            pc += __shfl_xor(pc, o, 64);
        }
        if (node < Nn) {
            ushort4 hv = make_ushort4(f2bf(acc[i][0]), f2bf(acc[i][1]),
                                      f2bf(acc[i][2]), f2bf(acc[i][3]));
            *(ushort4*)&h[(size_t)node * Dd + cg * 4] = hv;
            if (cg == 0) { ar[node] = pr; ac[node] = pc; }
        }
    }
}

// ---------------- bucket write-pointer init (fixed slack regions) ----------------
__global__ void bwp_init(int* __restrict__ bwp)
{
    int b = blockIdx.x * 256 + threadIdx.x;
    if (b < NBUCK) bwp[b] = b * BSLACK;
}

// ---------------- Pass A: LDS-binned edge staging into slack regions ----------------
__global__ __launch_bounds__(256, 2) void edge_bin(
    const int* __restrict__ rows, const int* __restrict__ cols,
    int* __restrict__ bwp, int2* __restrict__ binned)
{
    __shared__ int2 buf[NBUCK * BCAP];   // ~75 KB
    __shared__ int  lcnt[NBUCK];
    __shared__ int  lbase[NBUCK];

    const int tid = threadIdx.x;
    for (int b = tid; b < NBUCK; b += 256) lcnt[b] = 0;
    __syncthreads();

    const int per = (Ee + BINB - 1) / BINB;   // 3125
    const int e0 = blockIdx.x * per;
    const int e1 = min(e0 + per, Ee);

    for (int base = e0; base < e1; base += 256) {
        int e = base + tid;
        if (e < e1) {
            int r = rows[e], c = cols[e];
            int b = r >> BSH;
            int pos = atomicAdd(&lcnt[b], 1);
            if (pos < BCAP) buf[b * BCAP + pos] = make_int2(r, c);
            else {  // rare overflow: direct append
                int slot = atomicAdd(&bwp[b], 1);
                if (slot < (b + 1) * BSLACK) binned[slot] = make_int2(r, c);
            }
        }
    }
    __syncthreads();
    for (int b = tid; b < NBUCK; b += 256)
        lbase[b] = atomicAdd(&bwp[b], min(lcnt[b], BCAP));
    __syncthreads();
    int w = tid >> 6, lane = tid & 63;
    for (int b = w; b < NBUCK; b += 4) {
        int cnt = min(lcnt[b], BCAP);
        int gb = lbase[b];
        for (int i = lane; i < cnt; i += 64)
            binned[gb + i] = buf[b * BCAP + i];
    }
}

// ---------------- tiny: scan bucket fills -> CSR bucket bases ----------------
__global__ __launch_bounds__(512) void bucket_scan(const int* __restrict__ bwp,
                                                   int* __restrict__ boff,
                                                   int* __restrict__ off_last)
{
    __shared__ int ws[8];
    int tid = threadIdx.x;
    int v = (tid < NBUCK) ? (bwp[tid] - tid * BSLACK) : 0;
    int lane = tid & 63, w = tid >> 6;
    int incl = v;
    #pragma unroll
    for (int o = 1; o < 64; o <<= 1) {
        int y = __shfl_up(incl, o, 64);
        if (lane >= o) incl += y;
    }
    if (lane == 63) ws[w] = incl;
    __syncthreads();
    int pre = 0;
    for (int j = 0; j < w; ++j) pre += ws[j];
    if (tid <= NBUCK) boff[tid] = (tid < NBUCK) ? (pre + incl - v) : 0;
    if (tid == 511) { boff[NBUCK] = pre + incl; off_last[0] = pre + incl; }  // == Ee
}

// ---------------- Pass B: bucket-local CSR build + edge softmax weights ----------------
// One block per bucket (256 rows): per-node count + scan in LDS, scatter (col,ex).
__global__ __launch_bounds__(256) void bucket_to_csr(
    const int2* __restrict__ binned, const int* __restrict__ bwp,
    const int* __restrict__ boff,
    const float* __restrict__ ar, const float* __restrict__ ac,
    int* __restrict__ off, float2* __restrict__ ce_s)
{
    __shared__ int cnt[256];
    __shared__ int loff[256];
    __shared__ int wsh[4];

    const int b = blockIdx.x;
    const int base = b * BSLACK;
    const int n = min(bwp[b] - base, BSLACK);
    const int node0 = b << BSH;
    const int tid = threadIdx.x;

    cnt[tid] = 0;
    __syncthreads();

    for (int s = tid; s < n; s += 256) {
        int r = binned[base + s].x;
        atomicAdd(&cnt[r & 255], 1);
    }
    __syncthreads();

    // exclusive scan of cnt[256]
    int v = cnt[tid];
    int lane = tid & 63, w = tid >> 6;
    int incl = v;
    #pragma unroll
    for (int o = 1; o < 64; o <<= 1) {
        int y = __shfl_up(incl, o, 64);
        if (lane >= o) incl += y;
    }
    if (lane == 63) wsh[w] = incl;
    __syncthreads();
    int pre = 0;
    for (int j = 0; j < w; ++j) pre += wsh[j];
    int excl = pre + incl - v;
    loff[tid] = excl;
    if (node0 + tid < Nn) off[node0 + tid] = boff[b] + excl;
    __syncthreads();
    cnt[tid] = excl;   // becomes local write pointer
    __syncthreads();

    const int gbase = boff[b];
    for (int s = tid; s < n; s += 256) {
        int2 rc = binned[base + s];
        float sc = ar[rc.x] + ac[rc.y];
        sc = sc > 0.f ? sc : ALPHA * sc;
        float ex = __expf(sc);
        int pos = atomicAdd(&cnt[rc.x & 255], 1);
        ce_s[gbase + pos] = make_float2(__int_as_float(rc.y), ex);
    }
}

// ---------------- SpMM: out[i] = (1/sum_w) * sum_j w_ij * h[j,:] ----------------
__global__ __launch_bounds__(256) void spmm(
    const unsigned short* __restrict__ h, const int* __restrict__ off,
    const float2* __restrict__ ce_s, float* __restrict__ out)
{
    int tid  = threadIdx.x;
    int node = blockIdx.x * 16 + (tid >> 4);
    int lq   = tid & 15;
    if (node >= Nn) return;
    int s0 = off[node], s1 = off[node + 1];
    const ushort4* h4 = (const ushort4*)h;   // row = 16 ushort4
    float4 acc = make_float4(0.f, 0.f, 0.f, 0.f);
    float wsum = 0.f;
    for (int s = s0; s < s1; ++s) {
        float2 p = ce_s[s];
        int c = __float_as_int(p.x);
        float wgt = p.y;
        wsum += wgt;
        ushort4 hv = h4[(size_t)c * 16 + lq];
        acc.x = fmaf(wgt, bf2f(hv.x), acc.x);
        acc.y = fmaf(wgt, bf2f(hv.y), acc.y);
        acc.z = fmaf(wgt, bf2f(hv.z), acc.z);
        acc.w = fmaf(wgt, bf2f(hv.w), acc.w);
    }
    float inv = (s1 > s0) ? 1.f / wsum : 0.f;
    float4 o = make_float4(acc.x * inv, acc.y * inv, acc.z * inv, acc.w * inv);
    ((float4*)out)[(size_t)node * 16 + lq] = o;
}

// ---------------- launch ----------------
extern "C" void kernel_launch(void* const* d_in, const int* in_sizes, int n_in,
                              void* d_out, int out_size, void* d_ws, size_t ws_size,
                              hipStream_t stream)
{
    const float* x     = (const float*)d_in[0];
    const int*   rows  = (const int*)d_in[1];
    const int*   cols  = (const int*)d_in[2];
    const float* W     = (const float*)d_in[3];
    const float* a_row = (const float*)d_in[4];
    const float* a_col = (const float*)d_in[5];
    float* out = (float*)d_out;

    char* ws = (char*)d_ws;
    size_t o = 0;
    unsigned short* h = (unsigned short*)(ws + o); o += (size_t)Nn * Dd * 2;  // 12.8 MB
    float* ar   = (float*)(ws + o); o += (size_t)Nn * 4;
    float* ac   = (float*)(ws + o); o += (size_t)Nn * 4;
    int*   off  = (int*)(ws + o);   o += (size_t)(Nn + 4) * 4;
    int*   bwp  = (int*)(ws + o);   o += 512 * 4;
    int*   boff = (int*)(ws + o);   o += 512 * 4;
    float2* ce_s  = (float2*)(ws + o); o += (size_t)Ee * 8;           // 12.8 MB
    int2*   binned = (int2*)(ws + o);  o += (size_t)NBUCK * BSLACK * 8; // 25.6 MB

    bwp_init<<<2, 256, 0, stream>>>(bwp);
    edge_bin<<<BINB, 256, 0, stream>>>(rows, cols, bwp, binned);
    bucket_scan<<<1, 512, 0, stream>>>(bwp, boff, off + Nn);
    gemm_scores<<<(Nn + 63) / 64, 256, 0, stream>>>(x, W, a_row, a_col, h, ar, ac);
    bucket_to_csr<<<NBUCK, 256, 0, stream>>>(binned, bwp, boff, ar, ac, off, ce_s);
    spmm<<<(Nn + 15) / 16, 256, 0, stream>>>(h, off, ce_s, out);
}

// Round 5
// 239.308 us; speedup vs baseline: 1.5692x; 1.0582x over previous
//
#include <hip/hip_runtime.h>
#include <hip/hip_bf16.h>

constexpr int Nn = 100000;   // nodes
constexpr int Ee = 1600000;  // edges
constexpr int Fd = 128;      // in features
constexpr int Dd = 64;       // out features
constexpr float ALPHA = 0.2f;

constexpr int XPAD = 132;    // x-tile row pitch (floats)

constexpr int BSH    = 8;                              // 256 rows per bucket
constexpr int NBUCK  = (Nn + (1 << BSH) - 1) >> BSH;   // 391
constexpr int BSLACK = 8192;                           // slack region per bucket (mean 4096)
constexpr int BCAP   = 24;                             // LDS entries per bucket (mean 8)
constexpr int BINB   = 512;                            // edge_bin blocks

__device__ __forceinline__ unsigned short f2bf(float f) {  // RTNE
    unsigned int u = __float_as_uint(f);
    u += 0x7fffu + ((u >> 16) & 1u);
    return (unsigned short)(u >> 16);
}
__device__ __forceinline__ float bf2f(unsigned short s) {
    return __uint_as_float((unsigned int)s << 16);
}

// ---------------- GEMM: h(bf16) = x @ W, ar = h@a_row, ac = h@a_col ----------------
__global__ __launch_bounds__(256, 2) void gemm_scores(
    const float* __restrict__ x, const float* __restrict__ W,
    const float* __restrict__ a_row, const float* __restrict__ a_col,
    unsigned short* __restrict__ h, float* __restrict__ ar, float* __restrict__ ac)
{
    __shared__ float Ws[Fd * Dd];
    __shared__ float xs[64 * XPAD];
    __shared__ float as[2 * Dd];

    const int tid = threadIdx.x;
    for (int i = tid; i < Fd * Dd; i += 256) Ws[i] = W[i];
    if (tid < Dd) { as[tid] = a_row[tid]; as[Dd + tid] = a_col[tid]; }

    const int node0 = blockIdx.x * 64;
    {
        const float4* xg = (const float4*)(x + (size_t)node0 * Fd);
        #pragma unroll
        for (int it = 0; it < 8; ++it) {
            int g  = tid + 256 * it;
            int nd = g >> 5, k4 = g & 31;
            float4 v = make_float4(0.f, 0.f, 0.f, 0.f);
            if (node0 + nd < Nn) v = xg[g];
            *(float4*)&xs[nd * XPAD + k4 * 4] = v;
        }
    }
    __syncthreads();

    const int cg = tid & 15;
    const int ng = tid >> 4;
    float acc[4][4] = {};

    for (int k = 0; k < Fd; k += 4) {
        float xr[4][4];
        #pragma unroll
        for (int i = 0; i < 4; ++i) {
            float4 v = *(const float4*)&xs[(ng * 4 + i) * XPAD + k];
            xr[i][0] = v.x; xr[i][1] = v.y; xr[i][2] = v.z; xr[i][3] = v.w;
        }
        #pragma unroll
        for (int kk = 0; kk < 4; ++kk) {
            float4 wv = *(const float4*)&Ws[(k + kk) * Dd + cg * 4];
            float wr[4] = {wv.x, wv.y, wv.z, wv.w};
            #pragma unroll
            for (int i = 0; i < 4; ++i)
                #pragma unroll
                for (int j = 0; j < 4; ++j)
                    acc[i][j] = fmaf(xr[i][kk], wr[j], acc[i][j]);
        }
    }

    #pragma unroll
    for (int i = 0; i < 4; ++i) {
        int node = node0 + ng * 4 + i;
        float pr = acc[i][0] * as[cg * 4 + 0] + acc[i][1] * as[cg * 4 + 1]
                 + acc[i][2] * as[cg * 4 + 2] + acc[i][3] * as[cg * 4 + 3];
        float pc = acc[i][0] * as[Dd + cg * 4 + 0] + acc[i][1] * as[Dd + cg * 4 + 1]
                 + acc[i][2] * as[Dd + cg * 4 + 2] + acc[i][3] * as[Dd + cg * 4 + 3];
        #pragma unroll
        for (int o = 1; o < 16; o <<= 1) {
            pr += __shfl_xor(pr, o, 64);
            pc += __shfl_xor(pc, o, 64);
        }
        if (node < Nn) {
            ushort4 hv = make_ushort4(f2bf(acc[i][0]), f2bf(acc[i][1]),
                                      f2bf(acc[i][2]), f2bf(acc[i][3]));
            *(ushort4*)&h[(size_t)node * Dd + cg * 4] = hv;
            if (cg == 0) { ar[node] = pr; ac[node] = pc; }
        }
    }
}

// ---------------- bucket write-pointer init (fixed slack regions) ----------------
__global__ void bwp_init(int* __restrict__ bwp)
{
    int b = blockIdx.x * 256 + threadIdx.x;
    if (b < NBUCK) bwp[b] = b * BSLACK;
}

// ---------------- Pass A: LDS-binned edge staging into slack regions ----------------
__global__ __launch_bounds__(256, 2) void edge_bin(
    const int* __restrict__ rows, const int* __restrict__ cols,
    int* __restrict__ bwp, int2* __restrict__ binned)
{
    __shared__ int2 buf[NBUCK * BCAP];   // ~75 KB
    __shared__ int  lcnt[NBUCK];
    __shared__ int  lbase[NBUCK];

    const int tid = threadIdx.x;
    for (int b = tid; b < NBUCK; b += 256) lcnt[b] = 0;
    __syncthreads();

    const int per = (Ee + BINB - 1) / BINB;   // 3125
    const int e0 = blockIdx.x * per;
    const int e1 = min(e0 + per, Ee);

    for (int base = e0; base < e1; base += 256) {
        int e = base + tid;
        if (e < e1) {
            int r = rows[e], c = cols[e];
            int b = r >> BSH;
            int pos = atomicAdd(&lcnt[b], 1);
            if (pos < BCAP) buf[b * BCAP + pos] = make_int2(r, c);
            else {  // rare overflow: direct append
                int slot = atomicAdd(&bwp[b], 1);
                if (slot < (b + 1) * BSLACK) binned[slot] = make_int2(r, c);
            }
        }
    }
    __syncthreads();
    for (int b = tid; b < NBUCK; b += 256)
        lbase[b] = atomicAdd(&bwp[b], min(lcnt[b], BCAP));
    __syncthreads();
    int w = tid >> 6, lane = tid & 63;
    for (int b = w; b < NBUCK; b += 4) {
        int cnt = min(lcnt[b], BCAP);
        int gb = lbase[b];
        for (int i = lane; i < cnt; i += 64)
            binned[gb + i] = buf[b * BCAP + i];
    }
}

// ---------------- tiny: scan bucket fills -> CSR bucket bases ----------------
__global__ __launch_bounds__(512) void bucket_scan(const int* __restrict__ bwp,
                                                   int* __restrict__ boff,
                                                   int* __restrict__ off_last)
{
    __shared__ int ws[8];
    int tid = threadIdx.x;
    int v = (tid < NBUCK) ? (bwp[tid] - tid * BSLACK) : 0;
    int lane = tid & 63, w = tid >> 6;
    int incl = v;
    #pragma unroll
    for (int o = 1; o < 64; o <<= 1) {
        int y = __shfl_up(incl, o, 64);
        if (lane >= o) incl += y;
    }
    if (lane == 63) ws[w] = incl;
    __syncthreads();
    int pre = 0;
    for (int j = 0; j < w; ++j) pre += ws[j];
    if (tid <= NBUCK) boff[tid] = (tid < NBUCK) ? (pre + incl - v) : 0;
    if (tid == 511) { boff[NBUCK] = pre + incl; off_last[0] = pre + incl; }  // == Ee
}

// ---------------- Pass B: bucket-local CSR build + edge softmax weights ----------------
__global__ __launch_bounds__(256) void bucket_to_csr(
    const int2* __restrict__ binned, const int* __restrict__ bwp,
    const int* __restrict__ boff,
    const float* __restrict__ ar, const float* __restrict__ ac,
    int* __restrict__ off, float2* __restrict__ ce_s)
{
    __shared__ int cnt[256];
    __shared__ int wsh[4];

    const int b = blockIdx.x;
    const int base = b * BSLACK;
    const int n = min(bwp[b] - base, BSLACK);
    const int node0 = b << BSH;
    const int tid = threadIdx.x;

    cnt[tid] = 0;
    __syncthreads();

    for (int s = tid; s < n; s += 256) {
        int r = binned[base + s].x;
        atomicAdd(&cnt[r & 255], 1);
    }
    __syncthreads();

    // exclusive scan of cnt[256]
    int v = cnt[tid];
    int lane = tid & 63, w = tid >> 6;
    int incl = v;
    #pragma unroll
    for (int o = 1; o < 64; o <<= 1) {
        int y = __shfl_up(incl, o, 64);
        if (lane >= o) incl += y;
    }
    if (lane == 63) wsh[w] = incl;
    __syncthreads();
    int pre = 0;
    for (int j = 0; j < w; ++j) pre += wsh[j];
    int excl = pre + incl - v;
    if (node0 + tid < Nn) off[node0 + tid] = boff[b] + excl;
    __syncthreads();
    cnt[tid] = excl;   // becomes local write pointer
    __syncthreads();

    const int gbase = boff[b];
    for (int s = tid; s < n; s += 256) {
        int2 rc = binned[base + s];
        float sc = ar[rc.x] + ac[rc.y];
        sc = sc > 0.f ? sc : ALPHA * sc;
        float ex = __expf(sc);
        int pos = atomicAdd(&cnt[rc.x & 255], 1);
        ce_s[gbase + pos] = make_float2(__int_as_float(rc.y), ex);
    }
}

// ---------------- SpMM: out[i] = (1/sum_w) * sum_j w_ij * h[j,:] ----------------
// 16 lanes x float4 per node. Chunked: one coalesced ce_s load per 16 edges,
// shuffle-broadcast -> all 16 h-gather addresses ready at once (latency overlap).
__global__ __launch_bounds__(256) void spmm(
    const unsigned short* __restrict__ h, const int* __restrict__ off,
    const float2* __restrict__ ce_s, float* __restrict__ out)
{
    int tid  = threadIdx.x;
    int node = blockIdx.x * 16 + (tid >> 4);
    int lq   = tid & 15;
    if (node >= Nn) return;
    int s0 = off[node], s1 = off[node + 1];
    const ushort4* h4 = (const ushort4*)h;   // row = 16 ushort4
    float4 acc = make_float4(0.f, 0.f, 0.f, 0.f);
    float wsum = 0.f;
    const int baselane = (tid & 63) & ~15;   // group's lane 0 within the wave

    for (int s = s0; s < s1; s += 16) {
        int m = s1 - s;
        if (m >= 16) {
            float2 p = ce_s[s + lq];         // coalesced: 16 lanes, 16 consecutive entries
            #pragma unroll
            for (int j = 0; j < 16; ++j) {
                float cx  = __shfl(p.x, baselane + j, 64);
                float wgt = __shfl(p.y, baselane + j, 64);
                int c = __float_as_int(cx);
                ushort4 hv = h4[(size_t)c * 16 + lq];
                wsum += wgt;
                acc.x = fmaf(wgt, bf2f(hv.x), acc.x);
                acc.y = fmaf(wgt, bf2f(hv.y), acc.y);
                acc.z = fmaf(wgt, bf2f(hv.z), acc.z);
                acc.w = fmaf(wgt, bf2f(hv.w), acc.w);
            }
        } else {
            float2 p = (lq < m) ? ce_s[s + lq] : make_float2(0.f, 0.f);
            for (int j = 0; j < m; ++j) {
                float cx  = __shfl(p.x, baselane + j, 64);
                float wgt = __shfl(p.y, baselane + j, 64);
                int c = __float_as_int(cx);
                ushort4 hv = h4[(size_t)c * 16 + lq];
                wsum += wgt;
                acc.x = fmaf(wgt, bf2f(hv.x), acc.x);
                acc.y = fmaf(wgt, bf2f(hv.y), acc.y);
                acc.z = fmaf(wgt, bf2f(hv.z), acc.z);
                acc.w = fmaf(wgt, bf2f(hv.w), acc.w);
            }
        }
    }
    float inv = (s1 > s0) ? 1.f / wsum : 0.f;
    float4 o = make_float4(acc.x * inv, acc.y * inv, acc.z * inv, acc.w * inv);
    ((float4*)out)[(size_t)node * 16 + lq] = o;
}

// ---------------- launch ----------------
extern "C" void kernel_launch(void* const* d_in, const int* in_sizes, int n_in,
                              void* d_out, int out_size, void* d_ws, size_t ws_size,
                              hipStream_t stream)
{
    const float* x     = (const float*)d_in[0];
    const int*   rows  = (const int*)d_in[1];
    const int*   cols  = (const int*)d_in[2];
    const float* W     = (const float*)d_in[3];
    const float* a_row = (const float*)d_in[4];
    const float* a_col = (const float*)d_in[5];
    float* out = (float*)d_out;

    char* ws = (char*)d_ws;
    size_t o = 0;
    unsigned short* h = (unsigned short*)(ws + o); o += (size_t)Nn * Dd * 2;  // 12.8 MB
    float* ar   = (float*)(ws + o); o += (size_t)Nn * 4;
    float* ac   = (float*)(ws + o); o += (size_t)Nn * 4;
    int*   off  = (int*)(ws + o);   o += (size_t)(Nn + 4) * 4;
    int*   bwp  = (int*)(ws + o);   o += 512 * 4;
    int*   boff = (int*)(ws + o);   o += 512 * 4;
    float2* ce_s  = (float2*)(ws + o); o += (size_t)Ee * 8;             // 12.8 MB
    int2*   binned = (int2*)(ws + o);  o += (size_t)NBUCK * BSLACK * 8; // 25.6 MB

    bwp_init<<<2, 256, 0, stream>>>(bwp);
    edge_bin<<<BINB, 256, 0, stream>>>(rows, cols, bwp, binned);
    bucket_scan<<<1, 512, 0, stream>>>(bwp, boff, off + Nn);
    gemm_scores<<<(Nn + 63) / 64, 256, 0, stream>>>(x, W, a_row, a_col, h, ar, ac);
    bucket_to_csr<<<NBUCK, 256, 0, stream>>>(binned, bwp, boff, ar, ac, off, ce_s);
    spmm<<<(Nn + 15) / 16, 256, 0, stream>>>(h, off, ce_s, out);
}

// Round 6
// 217.607 us; speedup vs baseline: 1.7257x; 1.0997x over previous
//
#include <hip/hip_runtime.h>
#include <hip/hip_bf16.h>

constexpr int Nn = 100000;   // nodes
constexpr int Ee = 1600000;  // edges
constexpr int Fd = 128;      // in features
constexpr int Dd = 64;       // out features
constexpr float ALPHA = 0.2f;

constexpr int BSH    = 8;                              // 256 rows per bucket
constexpr int NBUCK  = (Nn + (1 << BSH) - 1) >> BSH;   // 391
constexpr int BSLACK = 8192;                           // slack region per bucket (mean 4096)
constexpr int BCAP   = 24;                             // LDS entries per bucket (mean 8)
constexpr int BINB   = 512;                            // edge_bin blocks

typedef __attribute__((ext_vector_type(8))) short bf16x8;   // 8 bf16 (4 VGPRs)
typedef __attribute__((ext_vector_type(4))) float f32x4;    // MFMA accumulator

__device__ __forceinline__ unsigned short f2bf(float f) {  // RTNE
    unsigned int u = __float_as_uint(f);
    u += 0x7fffu + ((u >> 16) & 1u);
    return (unsigned short)(u >> 16);
}
__device__ __forceinline__ float bf2f(unsigned short s) {
    return __uint_as_float((unsigned int)s << 16);
}

// ---------------- MFMA GEMM: h(bf16) = x @ W, ar = h@a_row, ac = h@a_col --------
// 256 thr = 4 waves; block tile 64 nodes x 64 cols; wave = 16 nodes x 64 cols.
// mfma_f32_16x16x32_bf16: A[m=lane&15][k=quad*8+j], B[n=lane&15][k=quad*8+j],
// C/D: row=quad*4+reg, col=lane&15 (m89-verified).
__global__ __launch_bounds__(256, 4) void gemm_scores(
    const float* __restrict__ x, const float* __restrict__ W,
    const float* __restrict__ a_row, const float* __restrict__ a_col,
    unsigned short* __restrict__ h, float* __restrict__ ar, float* __restrict__ ac)
{
    constexpr int HP = 136;              // LDS pitch (bf16): 68 words -> 2-way bank alias (free)
    __shared__ unsigned short xs[64 * HP];   // x tile, bf16 [node][k]  17.4 KB
    __shared__ unsigned short wt[64 * HP];   // W^T,   bf16 [d][k]      17.4 KB
    __shared__ float as_[2 * Dd];            // a_row | a_col

    const int tid = threadIdx.x;

    // stage W^T (one-time, 8192 floats, coalesced read / scattered 2B LDS write)
    #pragma unroll 4
    for (int it = 0; it < 32; ++it) {
        int idx = tid + 256 * it;
        int k = idx >> 6, d = idx & 63;
        wt[d * HP + k] = f2bf(W[idx]);
    }
    if (tid < 2 * Dd) as_[tid] = (tid < Dd) ? a_row[tid] : a_col[tid - Dd];

    // stage x tile as bf16 (float4 loads -> ushort4 LDS writes)
    const int node0 = blockIdx.x * 64;
    const float4* xg = (const float4*)(x + (size_t)node0 * Fd);
    #pragma unroll
    for (int it = 0; it < 8; ++it) {
        int g  = tid + 256 * it;
        int nd = g >> 5, k4 = g & 31;
        float4 v = make_float4(0.f, 0.f, 0.f, 0.f);
        if (node0 + nd < Nn) v = xg[g];
        ushort4 bv = make_ushort4(f2bf(v.x), f2bf(v.y), f2bf(v.z), f2bf(v.w));
        *(ushort4*)&xs[nd * HP + k4 * 4] = bv;
    }
    __syncthreads();

    const int lane = tid & 63;
    const int wid  = tid >> 6;
    const int nlo  = lane & 15;
    const int quad = lane >> 4;

    f32x4 acc[4] = {{0.f,0.f,0.f,0.f},{0.f,0.f,0.f,0.f},{0.f,0.f,0.f,0.f},{0.f,0.f,0.f,0.f}};
    const unsigned short* xrow = &xs[(wid * 16 + nlo) * HP + quad * 8];

    #pragma unroll
    for (int ks = 0; ks < 4; ++ks) {
        bf16x8 a = *(const bf16x8*)(xrow + ks * 32);
        #pragma unroll
        for (int t = 0; t < 4; ++t) {
            bf16x8 b = *(const bf16x8*)&wt[(t * 16 + nlo) * HP + quad * 8 + ks * 32];
            acc[t] = __builtin_amdgcn_mfma_f32_16x16x32_bf16(a, b, acc[t], 0, 0, 0);
        }
    }

    #pragma unroll
    for (int r = 0; r < 4; ++r) {
        int node = node0 + wid * 16 + quad * 4 + r;
        float pr = 0.f, pc = 0.f;
        #pragma unroll
        for (int t = 0; t < 4; ++t) {
            float v = acc[t][r];
            pr = fmaf(v, as_[t * 16 + nlo], pr);
            pc = fmaf(v, as_[Dd + t * 16 + nlo], pc);
        }
        #pragma unroll
        for (int o = 1; o < 16; o <<= 1) {   // reduce across the 16-lane quad
            pr += __shfl_xor(pr, o, 64);
            pc += __shfl_xor(pc, o, 64);
        }
        if (node < Nn) {
            #pragma unroll
            for (int t = 0; t < 4; ++t)
                h[(size_t)node * Dd + t * 16 + nlo] = f2bf(acc[t][r]);
            if (nlo == 0) { ar[node] = pr; ac[node] = pc; }
        }
    }
}

// ---------------- bucket write-pointer init (fixed slack regions) ----------------
__global__ void bwp_init(int* __restrict__ bwp)
{
    int b = blockIdx.x * 256 + threadIdx.x;
    if (b < NBUCK) bwp[b] = b * BSLACK;
}

// ---------------- Pass A: LDS-binned edge staging into slack regions ----------------
__global__ __launch_bounds__(256, 2) void edge_bin(
    const int* __restrict__ rows, const int* __restrict__ cols,
    int* __restrict__ bwp, int2* __restrict__ binned)
{
    __shared__ int2 buf[NBUCK * BCAP];   // ~75 KB
    __shared__ int  lcnt[NBUCK];
    __shared__ int  lbase[NBUCK];

    const int tid = threadIdx.x;
    for (int b = tid; b < NBUCK; b += 256) lcnt[b] = 0;
    __syncthreads();

    const int per = (Ee + BINB - 1) / BINB;   // 3125
    const int e0 = blockIdx.x * per;
    const int e1 = min(e0 + per, Ee);

    for (int base = e0; base < e1; base += 256) {
        int e = base + tid;
        if (e < e1) {
            int r = rows[e], c = cols[e];
            int b = r >> BSH;
            int pos = atomicAdd(&lcnt[b], 1);
            if (pos < BCAP) buf[b * BCAP + pos] = make_int2(r, c);
            else {  // rare overflow: direct append
                int slot = atomicAdd(&bwp[b], 1);
                if (slot < (b + 1) * BSLACK) binned[slot] = make_int2(r, c);
            }
        }
    }
    __syncthreads();
    for (int b = tid; b < NBUCK; b += 256)
        lbase[b] = atomicAdd(&bwp[b], min(lcnt[b], BCAP));
    __syncthreads();
    int w = tid >> 6, lane = tid & 63;
    for (int b = w; b < NBUCK; b += 4) {
        int cnt = min(lcnt[b], BCAP);
        int gb = lbase[b];
        for (int i = lane; i < cnt; i += 64)
            binned[gb + i] = buf[b * BCAP + i];
    }
}

// ---------------- tiny: scan bucket fills -> CSR bucket bases ----------------
__global__ __launch_bounds__(512) void bucket_scan(const int* __restrict__ bwp,
                                                   int* __restrict__ boff,
                                                   int* __restrict__ off_last)
{
    __shared__ int ws[8];
    int tid = threadIdx.x;
    int v = (tid < NBUCK) ? (bwp[tid] - tid * BSLACK) : 0;
    int lane = tid & 63, w = tid >> 6;
    int incl = v;
    #pragma unroll
    for (int o = 1; o < 64; o <<= 1) {
        int y = __shfl_up(incl, o, 64);
        if (lane >= o) incl += y;
    }
    if (lane == 63) ws[w] = incl;
    __syncthreads();
    int pre = 0;
    for (int j = 0; j < w; ++j) pre += ws[j];
    if (tid <= NBUCK) boff[tid] = (tid < NBUCK) ? (pre + incl - v) : 0;
    if (tid == 511) { boff[NBUCK] = pre + incl; off_last[0] = pre + incl; }  // == Ee
}

// ---------------- Pass B: bucket-local CSR build + edge softmax weights ----------------
__global__ __launch_bounds__(256) void bucket_to_csr(
    const int2* __restrict__ binned, const int* __restrict__ bwp,
    const int* __restrict__ boff,
    const float* __restrict__ ar, const float* __restrict__ ac,
    int* __restrict__ off, float2* __restrict__ ce_s)
{
    __shared__ int cnt[256];
    __shared__ int wsh[4];

    const int b = blockIdx.x;
    const int base = b * BSLACK;
    const int n = min(bwp[b] - base, BSLACK);
    const int node0 = b << BSH;
    const int tid = threadIdx.x;

    cnt[tid] = 0;
    __syncthreads();

    for (int s = tid; s < n; s += 256) {
        int r = binned[base + s].x;
        atomicAdd(&cnt[r & 255], 1);
    }
    __syncthreads();

    int v = cnt[tid];
    int lane = tid & 63, w = tid >> 6;
    int incl = v;
    #pragma unroll
    for (int o = 1; o < 64; o <<= 1) {
        int y = __shfl_up(incl, o, 64);
        if (lane >= o) incl += y;
    }
    if (lane == 63) wsh[w] = incl;
    __syncthreads();
    int pre = 0;
    for (int j = 0; j < w; ++j) pre += wsh[j];
    int excl = pre + incl - v;
    if (node0 + tid < Nn) off[node0 + tid] = boff[b] + excl;
    __syncthreads();
    cnt[tid] = excl;   // becomes local write pointer
    __syncthreads();

    const int gbase = boff[b];
    for (int s = tid; s < n; s += 256) {
        int2 rc = binned[base + s];
        float sc = ar[rc.x] + ac[rc.y];
        sc = sc > 0.f ? sc : ALPHA * sc;
        float ex = __expf(sc);
        int pos = atomicAdd(&cnt[rc.x & 255], 1);
        ce_s[gbase + pos] = make_float2(__int_as_float(rc.y), ex);
    }
}

// ---------------- SpMM: out[i] = (1/sum_w) * sum_j w_ij * h[j,:] ----------------
__global__ __launch_bounds__(256) void spmm(
    const unsigned short* __restrict__ h, const int* __restrict__ off,
    const float2* __restrict__ ce_s, float* __restrict__ out)
{
    int tid  = threadIdx.x;
    int node = blockIdx.x * 16 + (tid >> 4);
    int lq   = tid & 15;
    if (node >= Nn) return;
    int s0 = off[node], s1 = off[node + 1];
    const ushort4* h4 = (const ushort4*)h;   // row = 16 ushort4
    float4 acc = make_float4(0.f, 0.f, 0.f, 0.f);
    float wsum = 0.f;
    const int baselane = (tid & 63) & ~15;

    for (int s = s0; s < s1; s += 16) {
        int m = s1 - s;
        if (m >= 16) {
            float2 p = ce_s[s + lq];         // coalesced chunk load
            #pragma unroll
            for (int j = 0; j < 16; ++j) {
                float cx  = __shfl(p.x, baselane + j, 64);
                float wgt = __shfl(p.y, baselane + j, 64);
                int c = __float_as_int(cx);
                ushort4 hv = h4[(size_t)c * 16 + lq];
                wsum += wgt;
                acc.x = fmaf(wgt, bf2f(hv.x), acc.x);
                acc.y = fmaf(wgt, bf2f(hv.y), acc.y);
                acc.z = fmaf(wgt, bf2f(hv.z), acc.z);
                acc.w = fmaf(wgt, bf2f(hv.w), acc.w);
            }
        } else {
            float2 p = (lq < m) ? ce_s[s + lq] : make_float2(0.f, 0.f);
            for (int j = 0; j < m; ++j) {
                float cx  = __shfl(p.x, baselane + j, 64);
                float wgt = __shfl(p.y, baselane + j, 64);
                int c = __float_as_int(cx);
                ushort4 hv = h4[(size_t)c * 16 + lq];
                wsum += wgt;
                acc.x = fmaf(wgt, bf2f(hv.x), acc.x);
                acc.y = fmaf(wgt, bf2f(hv.y), acc.y);
                acc.z = fmaf(wgt, bf2f(hv.z), acc.z);
                acc.w = fmaf(wgt, bf2f(hv.w), acc.w);
            }
        }
    }
    float inv = (s1 > s0) ? 1.f / wsum : 0.f;
    float4 o = make_float4(acc.x * inv, acc.y * inv, acc.z * inv, acc.w * inv);
    ((float4*)out)[(size_t)node * 16 + lq] = o;
}

// ---------------- launch ----------------
extern "C" void kernel_launch(void* const* d_in, const int* in_sizes, int n_in,
                              void* d_out, int out_size, void* d_ws, size_t ws_size,
                              hipStream_t stream)
{
    const float* x     = (const float*)d_in[0];
    const int*   rows  = (const int*)d_in[1];
    const int*   cols  = (const int*)d_in[2];
    const float* W     = (const float*)d_in[3];
    const float* a_row = (const float*)d_in[4];
    const float* a_col = (const float*)d_in[5];
    float* out = (float*)d_out;

    char* ws = (char*)d_ws;
    size_t o = 0;
    unsigned short* h = (unsigned short*)(ws + o); o += (size_t)Nn * Dd * 2;  // 12.8 MB
    float* ar   = (float*)(ws + o); o += (size_t)Nn * 4;
    float* ac   = (float*)(ws + o); o += (size_t)Nn * 4;
    int*   off  = (int*)(ws + o);   o += (size_t)(Nn + 4) * 4;
    int*   bwp  = (int*)(ws + o);   o += 512 * 4;
    int*   boff = (int*)(ws + o);   o += 512 * 4;
    float2* ce_s  = (float2*)(ws + o); o += (size_t)Ee * 8;             // 12.8 MB
    int2*   binned = (int2*)(ws + o);  o += (size_t)NBUCK * BSLACK * 8; // 25.6 MB

    bwp_init<<<2, 256, 0, stream>>>(bwp);
    edge_bin<<<BINB, 256, 0, stream>>>(rows, cols, bwp, binned);
    bucket_scan<<<1, 512, 0, stream>>>(bwp, boff, off + Nn);
    gemm_scores<<<(Nn + 63) / 64, 256, 0, stream>>>(x, W, a_row, a_col, h, ar, ac);
    bucket_to_csr<<<NBUCK, 256, 0, stream>>>(binned, bwp, boff, ar, ac, off, ce_s);
    spmm<<<(Nn + 15) / 16, 256, 0, stream>>>(h, off, ce_s, out);
}

// Round 7
// 206.759 us; speedup vs baseline: 1.8162x; 1.0525x over previous
//
#include <hip/hip_runtime.h>
#include <hip/hip_bf16.h>

constexpr int Nn = 100000;   // nodes
constexpr int Ee = 1600000;  // edges
constexpr int Fd = 128;      // in features
constexpr int Dd = 64;       // out features
constexpr float ALPHA = 0.2f;

constexpr int BSH    = 8;                              // 256 rows per bucket
constexpr int NBUCK  = (Nn + (1 << BSH) - 1) >> BSH;   // 391
constexpr int BSLACK = 8192;                           // slack region per bucket (mean 4096)
constexpr int BCAP   = 24;                             // LDS entries per bucket (mean 8)
constexpr int BINB   = 512;                            // edge_bin blocks

constexpr int SPMM_LDSE = 768;   // LDS edge cap per block (mean 256 = Poisson, std 16)

typedef __attribute__((ext_vector_type(8))) short bf16x8;   // 8 bf16 (4 VGPRs)
typedef __attribute__((ext_vector_type(4))) float f32x4;    // MFMA accumulator

__device__ __forceinline__ unsigned short f2bf(float f) {  // RTNE
    unsigned int u = __float_as_uint(f);
    u += 0x7fffu + ((u >> 16) & 1u);
    return (unsigned short)(u >> 16);
}
__device__ __forceinline__ float bf2f(unsigned short s) {
    return __uint_as_float((unsigned int)s << 16);
}

// ---------------- MFMA GEMM: h(bf16) = x @ W, ar = h@a_row, ac = h@a_col --------
__global__ __launch_bounds__(256, 4) void gemm_scores(
    const float* __restrict__ x, const float* __restrict__ W,
    const float* __restrict__ a_row, const float* __restrict__ a_col,
    unsigned short* __restrict__ h, float* __restrict__ ar, float* __restrict__ ac)
{
    constexpr int HP = 136;              // LDS pitch (bf16): 2-way bank alias (free)
    __shared__ unsigned short xs[64 * HP];   // x tile, bf16 [node][k]
    __shared__ unsigned short wt[64 * HP];   // W^T,   bf16 [d][k]
    __shared__ float as_[2 * Dd];            // a_row | a_col

    const int tid = threadIdx.x;

    #pragma unroll 4
    for (int it = 0; it < 32; ++it) {
        int idx = tid + 256 * it;
        int k = idx >> 6, d = idx & 63;
        wt[d * HP + k] = f2bf(W[idx]);
    }
    if (tid < 2 * Dd) as_[tid] = (tid < Dd) ? a_row[tid] : a_col[tid - Dd];

    const int node0 = blockIdx.x * 64;
    const float4* xg = (const float4*)(x + (size_t)node0 * Fd);
    #pragma unroll
    for (int it = 0; it < 8; ++it) {
        int g  = tid + 256 * it;
        int nd = g >> 5, k4 = g & 31;
        float4 v = make_float4(0.f, 0.f, 0.f, 0.f);
        if (node0 + nd < Nn) v = xg[g];
        ushort4 bv = make_ushort4(f2bf(v.x), f2bf(v.y), f2bf(v.z), f2bf(v.w));
        *(ushort4*)&xs[nd * HP + k4 * 4] = bv;
    }
    __syncthreads();

    const int lane = tid & 63;
    const int wid  = tid >> 6;
    const int nlo  = lane & 15;
    const int quad = lane >> 4;

    f32x4 acc[4] = {{0.f,0.f,0.f,0.f},{0.f,0.f,0.f,0.f},{0.f,0.f,0.f,0.f},{0.f,0.f,0.f,0.f}};
    const unsigned short* xrow = &xs[(wid * 16 + nlo) * HP + quad * 8];

    #pragma unroll
    for (int ks = 0; ks < 4; ++ks) {
        bf16x8 a = *(const bf16x8*)(xrow + ks * 32);
        #pragma unroll
        for (int t = 0; t < 4; ++t) {
            bf16x8 b = *(const bf16x8*)&wt[(t * 16 + nlo) * HP + quad * 8 + ks * 32];
            acc[t] = __builtin_amdgcn_mfma_f32_16x16x32_bf16(a, b, acc[t], 0, 0, 0);
        }
    }

    #pragma unroll
    for (int r = 0; r < 4; ++r) {
        int node = node0 + wid * 16 + quad * 4 + r;
        float pr = 0.f, pc = 0.f;
        #pragma unroll
        for (int t = 0; t < 4; ++t) {
            float v = acc[t][r];
            pr = fmaf(v, as_[t * 16 + nlo], pr);
            pc = fmaf(v, as_[Dd + t * 16 + nlo], pc);
        }
        #pragma unroll
        for (int o = 1; o < 16; o <<= 1) {
            pr += __shfl_xor(pr, o, 64);
            pc += __shfl_xor(pc, o, 64);
        }
        if (node < Nn) {
            #pragma unroll
            for (int t = 0; t < 4; ++t)
                h[(size_t)node * Dd + t * 16 + nlo] = f2bf(acc[t][r]);
            if (nlo == 0) { ar[node] = pr; ac[node] = pc; }
        }
    }
}

// ---------------- bucket write-pointer init ----------------
__global__ void bwp_init(int* __restrict__ bwp)
{
    int b = blockIdx.x * 256 + threadIdx.x;
    if (b < NBUCK) bwp[b] = b * BSLACK;
}

// ---------------- Pass A: LDS-binned edge staging into slack regions ----------------
__global__ __launch_bounds__(256, 2) void edge_bin(
    const int* __restrict__ rows, const int* __restrict__ cols,
    int* __restrict__ bwp, int2* __restrict__ binned)
{
    __shared__ int2 buf[NBUCK * BCAP];   // ~75 KB
    __shared__ int  lcnt[NBUCK];
    __shared__ int  lbase[NBUCK];

    const int tid = threadIdx.x;
    for (int b = tid; b < NBUCK; b += 256) lcnt[b] = 0;
    __syncthreads();

    const int per = (Ee + BINB - 1) / BINB;   // 3125
    const int e0 = blockIdx.x * per;
    const int e1 = min(e0 + per, Ee);

    for (int base = e0; base < e1; base += 256) {
        int e = base + tid;
        if (e < e1) {
            int r = rows[e], c = cols[e];
            int b = r >> BSH;
            int pos = atomicAdd(&lcnt[b], 1);
            if (pos < BCAP) buf[b * BCAP + pos] = make_int2(r, c);
            else {
                int slot = atomicAdd(&bwp[b], 1);
                if (slot < (b + 1) * BSLACK) binned[slot] = make_int2(r, c);
            }
        }
    }
    __syncthreads();
    for (int b = tid; b < NBUCK; b += 256)
        lbase[b] = atomicAdd(&bwp[b], min(lcnt[b], BCAP));
    __syncthreads();
    int w = tid >> 6, lane = tid & 63;
    for (int b = w; b < NBUCK; b += 4) {
        int cnt = min(lcnt[b], BCAP);
        int gb = lbase[b];
        for (int i = lane; i < cnt; i += 64)
            binned[gb + i] = buf[b * BCAP + i];
    }
}

// ---------------- tiny: scan bucket fills -> CSR bucket bases ----------------
__global__ __launch_bounds__(512) void bucket_scan(const int* __restrict__ bwp,
                                                   int* __restrict__ boff,
                                                   int* __restrict__ off_last)
{
    __shared__ int ws[8];
    int tid = threadIdx.x;
    int v = (tid < NBUCK) ? (bwp[tid] - tid * BSLACK) : 0;
    int lane = tid & 63, w = tid >> 6;
    int incl = v;
    #pragma unroll
    for (int o = 1; o < 64; o <<= 1) {
        int y = __shfl_up(incl, o, 64);
        if (lane >= o) incl += y;
    }
    if (lane == 63) ws[w] = incl;
    __syncthreads();
    int pre = 0;
    for (int j = 0; j < w; ++j) pre += ws[j];
    if (tid <= NBUCK) boff[tid] = (tid < NBUCK) ? (pre + incl - v) : 0;
    if (tid == 511) { boff[NBUCK] = pre + incl; off_last[0] = pre + incl; }
}

// ---------------- Pass B: bucket-local CSR build + edge softmax weights ----------------
__global__ __launch_bounds__(256) void bucket_to_csr(
    const int2* __restrict__ binned, const int* __restrict__ bwp,
    const int* __restrict__ boff,
    const float* __restrict__ ar, const float* __restrict__ ac,
    int* __restrict__ off, float2* __restrict__ ce_s)
{
    __shared__ int cnt[256];
    __shared__ int wsh[4];

    const int b = blockIdx.x;
    const int base = b * BSLACK;
    const int n = min(bwp[b] - base, BSLACK);
    const int node0 = b << BSH;
    const int tid = threadIdx.x;

    cnt[tid] = 0;
    __syncthreads();

    for (int s = tid; s < n; s += 256) {
        int r = binned[base + s].x;
        atomicAdd(&cnt[r & 255], 1);
    }
    __syncthreads();

    int v = cnt[tid];
    int lane = tid & 63, w = tid >> 6;
    int incl = v;
    #pragma unroll
    for (int o = 1; o < 64; o <<= 1) {
        int y = __shfl_up(incl, o, 64);
        if (lane >= o) incl += y;
    }
    if (lane == 63) wsh[w] = incl;
    __syncthreads();
    int pre = 0;
    for (int j = 0; j < w; ++j) pre += wsh[j];
    int excl = pre + incl - v;
    if (node0 + tid < Nn) off[node0 + tid] = boff[b] + excl;
    __syncthreads();
    cnt[tid] = excl;   // local write pointer
    __syncthreads();

    const int gbase = boff[b];
    for (int s = tid; s < n; s += 256) {
        int2 rc = binned[base + s];
        float sc = ar[rc.x] + ac[rc.y];
        sc = sc > 0.f ? sc : ALPHA * sc;
        float ex = __expf(sc);
        int pos = atomicAdd(&cnt[rc.x & 255], 1);
        ce_s[gbase + pos] = make_float2(__int_as_float(rc.y), ex);
    }
}

// ---------------- SpMM: out[i] = (1/sum_w) * sum_j w_ij * h[j,:] ----------------
// Block = 16 nodes; the block's edges are CONTIGUOUS in ce_s (CSR) -> stage them
// into LDS with one coalesced burst, then same-address ds_read broadcasts per
// 16-lane group. No shuffles, no per-chunk global latency, 8-wide gather unroll.
__global__ __launch_bounds__(256) void spmm(
    const unsigned short* __restrict__ h, const int* __restrict__ off,
    const float2* __restrict__ ce_s, float* __restrict__ out)
{
    __shared__ float2 lce[SPMM_LDSE];   // 6 KB
    const int tid   = threadIdx.x;
    const int node0 = blockIdx.x * 16;

    const int gE0 = off[node0];
    const int gE1 = off[node0 + 16];    // node0+16 <= Nn always (6250*16 = Nn)
    const int n   = gE1 - gE0;
    const int nl  = min(n, SPMM_LDSE);
    for (int s = tid; s < nl; s += 256) lce[s] = ce_s[gE0 + s];
    __syncthreads();

    const int node = node0 + (tid >> 4);
    const int lq   = tid & 15;
    int s0 = off[node] - gE0, s1 = off[node + 1] - gE0;

    const ushort4* h4 = (const ushort4*)h;   // row = 16 ushort4
    float4 acc = make_float4(0.f, 0.f, 0.f, 0.f);
    float wsum = 0.f;

    int j = s0;
    const int mainEnd = min(s1, nl);
    for (; j + 8 <= mainEnd; j += 8) {
        float2 p[8];
        ushort4 hv[8];
        #pragma unroll
        for (int u = 0; u < 8; ++u) p[u] = lce[j + u];        // broadcast reads
        #pragma unroll
        for (int u = 0; u < 8; ++u)
            hv[u] = h4[(size_t)__float_as_int(p[u].x) * 16 + lq];  // 8 gathers in flight
        #pragma unroll
        for (int u = 0; u < 8; ++u) {
            float wgt = p[u].y;
            wsum += wgt;
            acc.x = fmaf(wgt, bf2f(hv[u].x), acc.x);
            acc.y = fmaf(wgt, bf2f(hv[u].y), acc.y);
            acc.z = fmaf(wgt, bf2f(hv[u].z), acc.z);
            acc.w = fmaf(wgt, bf2f(hv[u].w), acc.w);
        }
    }
    for (; j < s1; ++j) {
        float2 p = (j < nl) ? lce[j] : ce_s[gE0 + j];   // overflow fallback (never in practice)
        int c = __float_as_int(p.x);
        float wgt = p.y;
        wsum += wgt;
        ushort4 hv = h4[(size_t)c * 16 + lq];
        acc.x = fmaf(wgt, bf2f(hv.x), acc.x);
        acc.y = fmaf(wgt, bf2f(hv.y), acc.y);
        acc.z = fmaf(wgt, bf2f(hv.z), acc.z);
        acc.w = fmaf(wgt, bf2f(hv.w), acc.w);
    }

    float inv = (s1 > s0) ? 1.f / wsum : 0.f;
    float4 o = make_float4(acc.x * inv, acc.y * inv, acc.z * inv, acc.w * inv);
    ((float4*)out)[(size_t)node * 16 + lq] = o;
}

// ---------------- launch ----------------
extern "C" void kernel_launch(void* const* d_in, const int* in_sizes, int n_in,
                              void* d_out, int out_size, void* d_ws, size_t ws_size,
                              hipStream_t stream)
{
    const float* x     = (const float*)d_in[0];
    const int*   rows  = (const int*)d_in[1];
    const int*   cols  = (const int*)d_in[2];
    const float* W     = (const float*)d_in[3];
    const float* a_row = (const float*)d_in[4];
    const float* a_col = (const float*)d_in[5];
    float* out = (float*)d_out;

    char* ws = (char*)d_ws;
    size_t o = 0;
    unsigned short* h = (unsigned short*)(ws + o); o += (size_t)Nn * Dd * 2;  // 12.8 MB
    float* ar   = (float*)(ws + o); o += (size_t)Nn * 4;
    float* ac   = (float*)(ws + o); o += (size_t)Nn * 4;
    int*   off  = (int*)(ws + o);   o += (size_t)(Nn + 4) * 4;
    int*   bwp  = (int*)(ws + o);   o += 512 * 4;
    int*   boff = (int*)(ws + o);   o += 512 * 4;
    float2* ce_s  = (float2*)(ws + o); o += (size_t)Ee * 8;             // 12.8 MB
    int2*   binned = (int2*)(ws + o);  o += (size_t)NBUCK * BSLACK * 8; // 25.6 MB

    bwp_init<<<2, 256, 0, stream>>>(bwp);
    edge_bin<<<BINB, 256, 0, stream>>>(rows, cols, bwp, binned);
    bucket_scan<<<1, 512, 0, stream>>>(bwp, boff, off + Nn);
    gemm_scores<<<(Nn + 63) / 64, 256, 0, stream>>>(x, W, a_row, a_col, h, ar, ac);
    bucket_to_csr<<<NBUCK, 256, 0, stream>>>(binned, bwp, boff, ar, ac, off, ce_s);
    spmm<<<Nn / 16, 256, 0, stream>>>(h, off, ce_s, out);
}